// Round 1
// baseline (2102.241 us; speedup 1.0000x reference)
//
#include <hip/hip_runtime.h>
#include <cstdint>

// SlimmableMoE: B=4,S=1024,D=1024,E=8,F=4096,W=768,H=6,HD=128,TOPK=2
#define NE 8
#define NB 4
#define NS 1024
#define ND 1024
#define NF 4096
#define NW 768
#define NH 6
#define NHD 128
#define NTOK 4096   // B*S
#define EPS 1e-6f

typedef __attribute__((ext_vector_type(8))) short short8;   // 8 bf16 = 4 VGPR
typedef __attribute__((ext_vector_type(4))) float f32x4;
typedef __attribute__((ext_vector_type(4))) unsigned short u16x4;

typedef const __attribute__((address_space(1))) void gvoid_t;
typedef __attribute__((address_space(3))) void lvoid_t;

__device__ __forceinline__ void gload16(const void* g, void* l) {
  __builtin_amdgcn_global_load_lds((gvoid_t*)g, (lvoid_t*)l, 16, 0, 0);
}

__device__ __forceinline__ unsigned short f2b(float f) {
  union { float f; uint32_t u; } x; x.f = f;
  uint32_t r = x.u + 0x7fffu + ((x.u >> 16) & 1u);
  return (unsigned short)(r >> 16);
}

// ---------------- cast f32 slice -> bf16 (dst ld = cols) ----------------
__global__ __launch_bounds__(256, 4)
void cast2d(const float* __restrict__ src, int ldsrc, int rows, int cols4,
            unsigned short* __restrict__ dst) {
  long long n = (long long)rows * cols4;
  for (long long idx = (long long)blockIdx.x * blockDim.x + threadIdx.x; idx < n;
       idx += (long long)gridDim.x * blockDim.x) {
    int r = (int)(idx / cols4), c = (int)(idx % cols4);
    float4 v = *(const float4*)(src + (size_t)r * ldsrc + (size_t)c * 4);
    u16x4 o; o.x = f2b(v.x); o.y = f2b(v.y); o.z = f2b(v.z); o.w = f2b(v.w);
    *(u16x4*)(dst + idx * 4) = o;
  }
}

// ---------------- router: logits->softmax->top2->normalized gate ----------------
__global__ __launch_bounds__(256, 4)
void router_kernel(const float* __restrict__ x, const float* __restrict__ wr,
                   float* __restrict__ gate) {
  int lane = threadIdx.x & 63, wave = threadIdx.x >> 6;
  int t = blockIdx.x * 4 + wave;
  float acc[NE] = {};
  for (int i = 0; i < 16; ++i) {
    int d = lane + i * 64;
    float xv = x[(size_t)t * ND + d];
    const float* wp = wr + (size_t)d * NE;
    float4 w0 = *(const float4*)wp, w1 = *(const float4*)(wp + 4);
    acc[0] += xv * w0.x; acc[1] += xv * w0.y; acc[2] += xv * w0.z; acc[3] += xv * w0.w;
    acc[4] += xv * w1.x; acc[5] += xv * w1.y; acc[6] += xv * w1.z; acc[7] += xv * w1.w;
  }
#pragma unroll
  for (int e = 0; e < NE; ++e)
    for (int m = 1; m < 64; m <<= 1) acc[e] += __shfl_xor(acc[e], m);
  int i1 = 0; float v1 = acc[0];
#pragma unroll
  for (int e = 1; e < NE; ++e) if (acc[e] > v1) { v1 = acc[e]; i1 = e; }
  int i2 = -1; float v2 = -3.0e38f;
#pragma unroll
  for (int e = 0; e < NE; ++e) if (e != i1 && acc[e] > v2) { v2 = acc[e]; i2 = e; }
  float p2 = __expf(v2 - v1);          // p1 = 1
  float g1 = 1.0f / (1.0f + p2), g2 = p2 / (1.0f + p2);
  if (lane < NE)
    gate[(size_t)t * NE + lane] = (lane == i1) ? g1 : ((lane == i2) ? g2 : 0.0f);
}

// ---------------- GEMM: C[M,N] = A[M,K](bf16) * B[N,K](bf16)^T + bias ----------------
// EPI: 1 = f32 out, 2 = gelu->bf16 out, 3 = QKV (z<2: bf16 out; z==2: write V^T layout)
#define BM 128
#define BN 128
#define BK 64

__device__ __forceinline__ float gelu_exact(float v) {
  return 0.5f * v * (1.0f + erff(v * 0.70710678118654752f));
}

template <int EPI>
__global__ __launch_bounds__(256, 2)
void gemm_bt(const unsigned short* __restrict__ A,
             const unsigned short* B0, const unsigned short* B1, const unsigned short* B2,
             const float* bias0, const float* bias1, const float* bias2,
             void* out0, void* out1, void* out2,
             int M, int N, int K) {
  const int z = blockIdx.z;
  const unsigned short* Bw = (z == 0) ? B0 : ((z == 1) ? B1 : B2);
  const float* bias = (z == 0) ? bias0 : ((z == 1) ? bias1 : bias2);
  void* outp = (z == 0) ? out0 : ((z == 1) ? out1 : out2);

  __shared__ __align__(16) unsigned short As[BM * BK];
  __shared__ __align__(16) unsigned short Bs[BN * BK];

  const int tid = threadIdx.x, lane = tid & 63, wave = tid >> 6;
  const int lr = lane & 15, lg = lane >> 4;
  const int wr = wave >> 1, wc = wave & 1;
  const int bm = blockIdx.x, bn = blockIdx.y;

  f32x4 acc[4][4] = {};
  const int nkt = K / BK;

  for (int kt = 0; kt < nkt; ++kt) {
    __syncthreads();
#pragma unroll
    for (int p = 0; p < 4; ++p) {
      int o = p * 4096 + tid * 16;
      int row = o >> 7, cb = o & 127;
      int cbs = cb ^ ((row & 7) << 4);   // pre-swizzled source (rule #21)
      gload16((const char*)A + ((size_t)(bm * BM + row) * K + (size_t)kt * BK) * 2 + cbs,
              (char*)As + o);
      gload16((const char*)Bw + ((size_t)(bn * BN + row) * K + (size_t)kt * BK) * 2 + cbs,
              (char*)Bs + o);
    }
    __syncthreads();
#pragma unroll
    for (int kk = 0; kk < 2; ++kk) {
      short8 af[4], bfr[4];
#pragma unroll
      for (int i = 0; i < 4; ++i) {
        int rowa = wr * 64 + i * 16 + lr;
        af[i] = *(const short8*)((const char*)As + rowa * 128 +
                                 (((kk * 64 + lg * 16)) ^ ((rowa & 7) << 4)));
        int rowb = wc * 64 + i * 16 + lr;
        bfr[i] = *(const short8*)((const char*)Bs + rowb * 128 +
                                  (((kk * 64 + lg * 16)) ^ ((rowb & 7) << 4)));
      }
#pragma unroll
      for (int i = 0; i < 4; ++i)
#pragma unroll
        for (int j = 0; j < 4; ++j)
          acc[i][j] = __builtin_amdgcn_mfma_f32_16x16x32_bf16(af[i], bfr[j], acc[i][j], 0, 0, 0);
    }
  }

  // epilogue: C row = bm*128+wr*64+i*16+lg*4+r ; col = bn*128+wc*64+j*16+lr
#pragma unroll
  for (int i = 0; i < 4; ++i) {
    int m0 = bm * BM + wr * 64 + i * 16 + lg * 4;
#pragma unroll
    for (int j = 0; j < 4; ++j) {
      int n = bn * BN + wc * 64 + j * 16 + lr;
      float bb = bias[n];
      if (EPI == 3 && z == 2) {
        // V^T layout: vt[((b*NH+h)*NHD + d) * NS + s], 4 consecutive s per lane
        int b_ = m0 >> 10, s0 = m0 & 1023, h_ = n >> 7, d = n & 127;
        u16x4 w;
#pragma unroll
        for (int r = 0; r < 4; ++r) w[r] = f2b(acc[i][j][r] + bb);
        *(u16x4*)((unsigned short*)outp +
                  ((size_t)((b_ * NH + h_) * NHD + d)) * NS + s0) = w;
      } else if (EPI == 1) {
        float* o = (float*)outp;
#pragma unroll
        for (int r = 0; r < 4; ++r) o[(size_t)(m0 + r) * N + n] = acc[i][j][r] + bb;
      } else {
        unsigned short* o = (unsigned short*)outp;
#pragma unroll
        for (int r = 0; r < 4; ++r) {
          float v = acc[i][j][r] + bb;
          if (EPI == 2) v = gelu_exact(v);
          o[(size_t)(m0 + r) * N + n] = f2b(v);
        }
      }
    }
  }
}

// ---------------- fused flash attention ----------------
// grid (S/64, B*H); block 256 = 4 waves; each wave owns 16 q rows; K/V^T tiles (32 keys) shared.
__global__ __launch_bounds__(256, 2)
void attn_kernel(const unsigned short* __restrict__ Qg, const unsigned short* __restrict__ Kg,
                 const unsigned short* __restrict__ VTg, unsigned short* __restrict__ AOg) {
  __shared__ __align__(16) unsigned short Ks[32 * 128];   // [key][d] swizzled
  __shared__ __align__(16) unsigned short VTs[128 * 32];  // [d][key] swizzled
  __shared__ __align__(16) unsigned short Ps[4 * 512];    // per-wave 16x32 bf16

  const int tid = threadIdx.x, lane = tid & 63, wave = tid >> 6;
  const int lr = lane & 15, lg = lane >> 4;
  const int qb = blockIdx.x, bh = blockIdx.y;
  const int b = bh / NH, h = bh % NH;
  const float cexp = 1.4426950408889634f / sqrtf((float)NHD);

  // Q fragments (input-side row = lr)
  int tq = b * NS + qb * 64 + wave * 16 + lr;
  short8 qf[4];
#pragma unroll
  for (int kk = 0; kk < 4; ++kk)
    qf[kk] = *(const short8*)(Qg + (size_t)tq * NW + h * NHD + kk * 32 + lg * 8);

  f32x4 accv[8] = {};
  float mr[4] = {-3.0e38f, -3.0e38f, -3.0e38f, -3.0e38f};
  float ls[4] = {};

  for (int kt = 0; kt < NS / 32; ++kt) {
    __syncthreads();
#pragma unroll
    for (int p = 0; p < 2; ++p) {   // stage K tile 32x128 bf16 (8KB)
      int o = p * 4096 + tid * 16;
      int row = o >> 8, cb = o & 255;
      gload16((const char*)Kg + ((size_t)(b * NS + kt * 32 + row) * NW + h * NHD) * 2 +
                  (cb ^ ((row & 7) << 4)),
              (char*)Ks + o);
    }
#pragma unroll
    for (int p = 0; p < 2; ++p) {   // stage V^T tile 128x32 bf16 (8KB)
      int o = p * 4096 + tid * 16;
      int d = o >> 6, cb = o & 63;
      gload16((const char*)VTg + ((size_t)(bh * NHD + d) * NS + kt * 32) * 2 +
                  (cb ^ ((d & 3) << 4)),
              (char*)VTs + o);
    }
    __syncthreads();

    // scores: S^[q][key] for 32 keys
    f32x4 s[2] = {};
#pragma unroll
    for (int kg = 0; kg < 2; ++kg)
#pragma unroll
      for (int kk = 0; kk < 4; ++kk) {
        int row = kg * 16 + lr;
        short8 kf = *(const short8*)((const char*)Ks + row * 256 +
                                     ((kk * 64 + lg * 16) ^ ((row & 7) << 4)));
        s[kg] = __builtin_amdgcn_mfma_f32_16x16x32_bf16(qf[kk], kf, s[kg], 0, 0, 0);
      }

    // online softmax (lane holds q = wave*16+lg*4+r, key = kg*16+lr)
    float pv[2][4];
#pragma unroll
    for (int r = 0; r < 4; ++r) {
      float mt = fmaxf(s[0][r], s[1][r]);
#pragma unroll
      for (int m = 1; m < 16; m <<= 1) mt = fmaxf(mt, __shfl_xor(mt, m));
      float mn = fmaxf(mr[r], mt);
      float sc = exp2f((mr[r] - mn) * cexp);
      mr[r] = mn;
      float p0 = exp2f((s[0][r] - mn) * cexp);
      float p1 = exp2f((s[1][r] - mn) * cexp);
      pv[0][r] = p0; pv[1][r] = p1;
      float ps = p0 + p1;
#pragma unroll
      for (int m = 1; m < 16; m <<= 1) ps += __shfl_xor(ps, m);
      ls[r] = ls[r] * sc + ps;
#pragma unroll
      for (int dg = 0; dg < 8; ++dg) accv[dg][r] *= sc;
    }

    // P -> LDS (per-wave private), read back as A-fragment
    unsigned short* pw = Ps + wave * 512;
#pragma unroll
    for (int kg = 0; kg < 2; ++kg)
#pragma unroll
      for (int r = 0; r < 4; ++r)
        pw[(lg * 4 + r) * 32 + kg * 16 + lr] = f2b(pv[kg][r]);
    short8 pf = *(const short8*)((const char*)pw + lr * 64 + lg * 16);

    // PV: O[q][d] += P(16x32) * V(32x128)
#pragma unroll
    for (int dg = 0; dg < 8; ++dg) {
      int d = dg * 16 + lr;
      short8 vf = *(const short8*)((const char*)VTs + d * 64 +
                                   ((lg * 16) ^ ((d & 3) << 4)));
      accv[dg] = __builtin_amdgcn_mfma_f32_16x16x32_bf16(pf, vf, accv[dg], 0, 0, 0);
    }
  }

#pragma unroll
  for (int r = 0; r < 4; ++r) {
    int t = b * NS + qb * 64 + wave * 16 + lg * 4 + r;
    float inv = 1.0f / ls[r];
#pragma unroll
    for (int dg = 0; dg < 8; ++dg)
      AOg[(size_t)t * NW + h * NHD + dg * 16 + lr] = f2b(accv[dg][r] * inv);
  }
}

// ---------------- residual + RMSNorm (writes f32 + bf16) ----------------
__global__ __launch_bounds__(256, 4)
void rmsnorm_res(const float* __restrict__ x, const float* __restrict__ oo,
                 float* __restrict__ x1f, unsigned short* __restrict__ x1b) {
  __shared__ float red[4];
  int t = blockIdx.x, c = threadIdx.x;
  int lane = c & 63, wave = c >> 6;
  float v[3]; float ss = 0.0f;
#pragma unroll
  for (int i = 0; i < 3; ++i) {
    int col = c + i * 256;
    float a = x[(size_t)t * ND + col] + oo[(size_t)t * NW + col];
    v[i] = a; ss += a * a;
  }
#pragma unroll
  for (int m = 1; m < 64; m <<= 1) ss += __shfl_xor(ss, m);
  if (lane == 0) red[wave] = ss;
  __syncthreads();
  float tot = red[0] + red[1] + red[2] + red[3];
  float scale = rsqrtf(tot / (float)NW + EPS);
#pragma unroll
  for (int i = 0; i < 3; ++i) {
    int col = c + i * 256;
    float a = v[i] * scale;
    x1f[(size_t)t * NW + col] = a;
    x1b[(size_t)t * NW + col] = f2b(a);
  }
}

// ---------------- final: rmsnorm(x1+f) * gate -> accumulate into out ----------------
__global__ __launch_bounds__(256, 4)
void final_acc(const float* __restrict__ x1f, const float* __restrict__ ff,
               const float* __restrict__ gate, int e, float* __restrict__ out) {
  int t = blockIdx.x;
  float g = gate[(size_t)t * NE + e];
  if (g == 0.0f) return;
  __shared__ float red[4];
  int c = threadIdx.x, lane = c & 63, wave = c >> 6;
  float v[3]; float ss = 0.0f;
#pragma unroll
  for (int i = 0; i < 3; ++i) {
    int col = c + i * 256;
    float a = x1f[(size_t)t * NW + col] + ff[(size_t)t * NW + col];
    v[i] = a; ss += a * a;
  }
#pragma unroll
  for (int m = 1; m < 64; m <<= 1) ss += __shfl_xor(ss, m);
  if (lane == 0) red[wave] = ss;
  __syncthreads();
  float tot = red[0] + red[1] + red[2] + red[3];
  float scale = rsqrtf(tot / (float)NW + EPS) * g;
#pragma unroll
  for (int i = 0; i < 3; ++i) {
    int col = c + i * 256;
    out[(size_t)t * ND + col] += v[i] * scale;
  }
}

// ---------------- host ----------------
extern "C" void kernel_launch(void* const* d_in, const int* in_sizes, int n_in,
                              void* d_out, int out_size, void* d_ws, size_t ws_size,
                              hipStream_t stream) {
  (void)in_sizes; (void)n_in; (void)ws_size;
  const float* x  = (const float*)d_in[0];
  const float* wr = (const float*)d_in[1];
  const float* qw = (const float*)d_in[2];
  const float* qb = (const float*)d_in[3];
  const float* kw = (const float*)d_in[4];
  const float* kb = (const float*)d_in[5];
  const float* vw = (const float*)d_in[6];
  const float* vb = (const float*)d_in[7];
  const float* ow = (const float*)d_in[8];
  const float* ob = (const float*)d_in[9];
  const float* w1 = (const float*)d_in[10];
  const float* b1 = (const float*)d_in[11];
  const float* w2 = (const float*)d_in[12];
  const float* b2 = (const float*)d_in[13];
  float* out = (float*)d_out;
  char* ws = (char*)d_ws;

  size_t off = 0;
  auto alloc = [&](size_t bytes) {
    void* p = ws + off;
    off += (bytes + 255) & ~(size_t)255;
    return p;
  };
  float* gate = (float*)alloc((size_t)NTOK * NE * 4);
  unsigned short* xs  = (unsigned short*)alloc((size_t)NTOK * NW * 2);
  unsigned short* wqb = (unsigned short*)alloc((size_t)NW * NW * 2);
  unsigned short* wkb = (unsigned short*)alloc((size_t)NW * NW * 2);
  unsigned short* wvb = (unsigned short*)alloc((size_t)NW * NW * 2);
  unsigned short* wob = (unsigned short*)alloc((size_t)NW * NW * 2);
  unsigned short* w1b = (unsigned short*)alloc((size_t)NF * NW * 2);
  unsigned short* w2b = (unsigned short*)alloc((size_t)NW * NF * 2);
  float* x1f = (float*)alloc((size_t)NTOK * NW * 4);
  unsigned short* x1b = (unsigned short*)alloc((size_t)NTOK * NW * 2);
  float* ff = (float*)alloc((size_t)NTOK * NW * 4);
  // scratch union: {q,k,vt,ao (bf16), oo (f32)} during attention phase; h (bf16) during FFN
  char* scr = (char*)alloc(37748736);
  unsigned short* qg  = (unsigned short*)scr;
  unsigned short* kg  = (unsigned short*)(scr + 6291456);
  unsigned short* vtg = (unsigned short*)(scr + 12582912);
  unsigned short* aog = (unsigned short*)(scr + 18874368);
  float* oo = (float*)(scr + 25165824);
  unsigned short* hb = (unsigned short*)scr;   // 32MB, aliases q..oo

  hipMemsetAsync(d_out, 0, (size_t)out_size * 4, stream);
  router_kernel<<<dim3(NTOK / 4), 256, 0, stream>>>(x, wr, gate);
  cast2d<<<dim3(1024), 256, 0, stream>>>(x, ND, NTOK, NW / 4, xs);

  for (int e = 0; e < NE; ++e) {
    cast2d<<<dim3(512), 256, 0, stream>>>(qw + (size_t)e * ND * ND, ND, NW, NW / 4, wqb);
    cast2d<<<dim3(512), 256, 0, stream>>>(kw + (size_t)e * ND * ND, ND, NW, NW / 4, wkb);
    cast2d<<<dim3(512), 256, 0, stream>>>(vw + (size_t)e * ND * ND, ND, NW, NW / 4, wvb);
    cast2d<<<dim3(512), 256, 0, stream>>>(ow + (size_t)e * ND * ND, ND, NW, NW / 4, wob);
    cast2d<<<dim3(1024), 256, 0, stream>>>(w1 + (size_t)e * NF * ND, ND, NF, NW / 4, w1b);
    cast2d<<<dim3(1024), 256, 0, stream>>>(w2 + (size_t)e * ND * NF, NF, NW, NF / 4, w2b);

    // QKV fused (z=0:Q bf16, z=1:K bf16, z=2:V -> V^T layout)
    gemm_bt<3><<<dim3(32, 6, 3), 256, 0, stream>>>(
        xs, wqb, wkb, wvb,
        qb + (size_t)e * ND, kb + (size_t)e * ND, vb + (size_t)e * ND,
        qg, kg, vtg, NTOK, NW, NW);

    attn_kernel<<<dim3(16, NB * NH), 256, 0, stream>>>(qg, kg, vtg, aog);

    gemm_bt<1><<<dim3(32, 6, 1), 256, 0, stream>>>(
        aog, wob, wob, wob,
        ob + (size_t)e * ND, ob + (size_t)e * ND, ob + (size_t)e * ND,
        oo, oo, oo, NTOK, NW, NW);

    rmsnorm_res<<<dim3(NTOK), 256, 0, stream>>>(x, oo, x1f, x1b);

    gemm_bt<2><<<dim3(32, 32, 1), 256, 0, stream>>>(
        x1b, w1b, w1b, w1b,
        b1 + (size_t)e * NF, b1 + (size_t)e * NF, b1 + (size_t)e * NF,
        hb, hb, hb, NTOK, NF, NW);

    gemm_bt<1><<<dim3(32, 6, 1), 256, 0, stream>>>(
        hb, w2b, w2b, w2b,
        b2 + (size_t)e * ND, b2 + (size_t)e * ND, b2 + (size_t)e * ND,
        ff, ff, ff, NTOK, NW, NF);

    final_acc<<<dim3(NTOK), 256, 0, stream>>>(x1f, ff, gate, e, out);
  }
}

// Round 2
// 1436.593 us; speedup vs baseline: 1.4634x; 1.4634x over previous
//
#include <hip/hip_runtime.h>
#include <cstdint>

// SlimmableMoE: B=4,S=1024,D=1024,E=8,F=4096,W=768,H=6,HD=128,TOPK=2
#define NE 8
#define NB 4
#define NS 1024
#define ND 1024
#define NF 4096
#define NW 768
#define NH 6
#define NHD 128
#define NTOK 4096   // B*S
#define NBH 24      // B*H
#define EPS 1e-6f

typedef unsigned short ush;
typedef __attribute__((ext_vector_type(8))) short short8;   // 8 bf16 = 4 VGPR
typedef __attribute__((ext_vector_type(4))) float f32x4;
typedef __attribute__((ext_vector_type(4))) unsigned short u16x4;

typedef const __attribute__((address_space(1))) void gvoid_t;
typedef __attribute__((address_space(3))) void lvoid_t;

__device__ __forceinline__ void gload16(const void* g, void* l) {
  __builtin_amdgcn_global_load_lds((gvoid_t*)g, (lvoid_t*)l, 16, 0, 0);
}

__device__ __forceinline__ ush f2b(float f) {
  union { float f; uint32_t u; } x; x.f = f;
  uint32_t r = x.u + 0x7fffu + ((x.u >> 16) & 1u);
  return (ush)(r >> 16);
}
__device__ __forceinline__ float b2f(ush u) {
  union { uint32_t u; float f; } x; x.u = (uint32_t)u << 16;
  return x.f;
}

// ---------------- cast f32 slice -> bf16 (dst ld = cols) ----------------
__global__ __launch_bounds__(256, 4)
void cast2d(const float* __restrict__ src, int ldsrc, int rows, int cols4,
            ush* __restrict__ dst) {
  long long n = (long long)rows * cols4;
  for (long long idx = (long long)blockIdx.x * blockDim.x + threadIdx.x; idx < n;
       idx += (long long)gridDim.x * blockDim.x) {
    int r = (int)(idx / cols4), c = (int)(idx % cols4);
    float4 v = *(const float4*)(src + (size_t)r * ldsrc + (size_t)c * 4);
    u16x4 o; o.x = f2b(v.x); o.y = f2b(v.y); o.z = f2b(v.z); o.w = f2b(v.w);
    *(u16x4*)(dst + idx * 4) = o;
  }
}

// ---------------- fused per-expert weight cast (6 tensors, 1 launch) ----------------
__global__ __launch_bounds__(256, 4)
void cast_expert(const float* __restrict__ qw, const float* __restrict__ kw,
                 const float* __restrict__ vw, const float* __restrict__ ow,
                 const float* __restrict__ w1, const float* __restrict__ w2,
                 ush* dq, ush* dk, ush* dv, ush* dwo, ush* d1, ush* d2) {
  const int Q4 = 147456;   // 768*768/4
  const int W14 = 786432;  // 4096*768/4  (== 768*4096/4)
  const int total = 4 * Q4 + 2 * W14;
  for (int u = blockIdx.x * 256 + threadIdx.x; u < total; u += gridDim.x * 256) {
    const float* src; ush* dst; int ldsrc, cols4, rel;
    if (u < 4 * Q4) {
      int which = u / Q4; rel = u - which * Q4;
      src = (which == 0) ? qw : (which == 1) ? kw : (which == 2) ? vw : ow;
      dst = (which == 0) ? dq : (which == 1) ? dk : (which == 2) ? dv : dwo;
      ldsrc = 1024; cols4 = 192;
    } else if (u < 4 * Q4 + W14) {
      rel = u - 4 * Q4; src = w1; dst = d1; ldsrc = 1024; cols4 = 192;
    } else {
      rel = u - 4 * Q4 - W14; src = w2; dst = d2; ldsrc = 4096; cols4 = 1024;
    }
    int r = rel / cols4, c = rel - r * cols4;
    float4 v = *(const float4*)(src + (size_t)r * ldsrc + (size_t)c * 4);
    u16x4 o; o.x = f2b(v.x); o.y = f2b(v.y); o.z = f2b(v.z); o.w = f2b(v.w);
    *(u16x4*)(dst + (size_t)rel * 4) = o;
  }
}

// ---------------- router: logits->softmax->top2->normalized gate ----------------
__global__ __launch_bounds__(256, 4)
void router_kernel(const float* __restrict__ x, const float* __restrict__ wr,
                   float* __restrict__ gate) {
  int lane = threadIdx.x & 63, wave = threadIdx.x >> 6;
  int t = blockIdx.x * 4 + wave;
  float acc[NE] = {};
  for (int i = 0; i < 16; ++i) {
    int d = lane + i * 64;
    float xv = x[(size_t)t * ND + d];
    const float* wp = wr + (size_t)d * NE;
    float4 w0 = *(const float4*)wp, w1 = *(const float4*)(wp + 4);
    acc[0] += xv * w0.x; acc[1] += xv * w0.y; acc[2] += xv * w0.z; acc[3] += xv * w0.w;
    acc[4] += xv * w1.x; acc[5] += xv * w1.y; acc[6] += xv * w1.z; acc[7] += xv * w1.w;
  }
#pragma unroll
  for (int e = 0; e < NE; ++e)
    for (int m = 1; m < 64; m <<= 1) acc[e] += __shfl_xor(acc[e], m);
  int i1 = 0; float v1 = acc[0];
#pragma unroll
  for (int e = 1; e < NE; ++e) if (acc[e] > v1) { v1 = acc[e]; i1 = e; }
  int i2 = -1; float v2 = -3.0e38f;
#pragma unroll
  for (int e = 0; e < NE; ++e) if (e != i1 && acc[e] > v2) { v2 = acc[e]; i2 = e; }
  float p2 = __expf(v2 - v1);          // p1 = 1
  float g1 = 1.0f / (1.0f + p2), g2 = p2 / (1.0f + p2);
  if (lane < NE)
    gate[(size_t)t * NE + lane] = (lane == i1) ? g1 : ((lane == i2) ? g2 : 0.0f);
}

// ---------------- GEMM: C[M,N] = A[M,K](bf16) * B[N,K](bf16)^T + bias ----------------
// EPI: 0 = bf16 out (+bias), 2 = gelu->bf16, 3 = QKV (z<2: bf16; z==2: V^T layout)
// mode 0: z selects (B,bias,out) triple, full K=klen from 0.
// mode 1: split-K; z selects k-chunk [z*klen, (z+1)*klen); out = out0 + z*M*N (bf16 partial);
//         bias only added to partial z==0.
#define BM 128
#define BN 128
#define BK 64

__device__ __forceinline__ float gelu_exact(float v) {
  return 0.5f * v * (1.0f + erff(v * 0.70710678118654752f));
}

template <int EPI>
__global__ __launch_bounds__(256, 2)
void gemm_bt(const ush* __restrict__ A,
             const ush* B0, const ush* B1, const ush* B2,
             const float* bias0, const float* bias1, const float* bias2,
             void* out0, void* out1, void* out2,
             int M, int N, int Kld, int klen, int mode) {
  const int z = blockIdx.z;
  const ush* Bw; const float* bias; void* outp; int koff;
  if (mode == 0) {
    Bw = (z == 0) ? B0 : ((z == 1) ? B1 : B2);
    bias = (z == 0) ? bias0 : ((z == 1) ? bias1 : bias2);
    outp = (z == 0) ? out0 : ((z == 1) ? out1 : out2);
    koff = 0;
  } else {
    Bw = B0;
    bias = (z == 0) ? bias0 : nullptr;
    outp = (void*)((ush*)out0 + (size_t)z * M * N);
    koff = z * klen;
  }

  __shared__ __align__(16) ush As[BM * BK];
  __shared__ __align__(16) ush Bs[BN * BK];

  const int tid = threadIdx.x, lane = tid & 63, wave = tid >> 6;
  const int lr = lane & 15, lg = lane >> 4;
  const int wr = wave >> 1, wc = wave & 1;
  const int bm = blockIdx.x, bn = blockIdx.y;

  f32x4 acc[4][4] = {};
  const int nkt = klen / BK;

  for (int kt = 0; kt < nkt; ++kt) {
    __syncthreads();
#pragma unroll
    for (int p = 0; p < 4; ++p) {
      int o = p * 4096 + tid * 16;
      int row = o >> 7, cb = o & 127;
      int cbs = cb ^ ((row & 7) << 4);   // pre-swizzled source (rule #21)
      gload16((const char*)A + ((size_t)(bm * BM + row) * Kld + koff + (size_t)kt * BK) * 2 + cbs,
              (char*)As + o);
      gload16((const char*)Bw + ((size_t)(bn * BN + row) * Kld + koff + (size_t)kt * BK) * 2 + cbs,
              (char*)Bs + o);
    }
    __syncthreads();
#pragma unroll
    for (int kk = 0; kk < 2; ++kk) {
      short8 af[4], bfr[4];
#pragma unroll
      for (int i = 0; i < 4; ++i) {
        int rowa = wr * 64 + i * 16 + lr;
        af[i] = *(const short8*)((const char*)As + rowa * 128 +
                                 (((kk * 64 + lg * 16)) ^ ((rowa & 7) << 4)));
        int rowb = wc * 64 + i * 16 + lr;
        bfr[i] = *(const short8*)((const char*)Bs + rowb * 128 +
                                  (((kk * 64 + lg * 16)) ^ ((rowb & 7) << 4)));
      }
#pragma unroll
      for (int i = 0; i < 4; ++i)
#pragma unroll
        for (int j = 0; j < 4; ++j)
          acc[i][j] = __builtin_amdgcn_mfma_f32_16x16x32_bf16(af[i], bfr[j], acc[i][j], 0, 0, 0);
    }
  }

  // epilogue: C row = bm*128+wr*64+i*16+lg*4+r ; col = bn*128+wc*64+j*16+lr
#pragma unroll
  for (int i = 0; i < 4; ++i) {
    int m0 = bm * BM + wr * 64 + i * 16 + lg * 4;
#pragma unroll
    for (int j = 0; j < 4; ++j) {
      int n = bn * BN + wc * 64 + j * 16 + lr;
      float bb = bias ? bias[n] : 0.0f;
      if (EPI == 3 && z == 2) {
        // V^T layout: vt[((b*NH+h)*NHD + d) * NS + s], 4 consecutive s per lane
        int b_ = m0 >> 10, s0 = m0 & 1023, h_ = n >> 7, d = n & 127;
        u16x4 w;
#pragma unroll
        for (int r = 0; r < 4; ++r) w[r] = f2b(acc[i][j][r] + bb);
        *(u16x4*)((ush*)outp + ((size_t)((b_ * NH + h_) * NHD + d)) * NS + s0) = w;
      } else {
        ush* o = (ush*)outp;
#pragma unroll
        for (int r = 0; r < 4; ++r) {
          float v = acc[i][j][r] + bb;
          if (EPI == 2) v = gelu_exact(v);
          o[(size_t)(m0 + r) * N + n] = f2b(v);
        }
      }
    }
  }
}

// ---------------- flash attention v2: KVBLK=64, split-KV x4, defer-max ----------------
// grid (S/64, NBH*4); block 256 = 4 waves; wave owns 16 q rows; each block does 256 keys.
__global__ __launch_bounds__(256, 3)
void attn2(const ush* __restrict__ Qg, const ush* __restrict__ Kg,
           const ush* __restrict__ VTg,
           ush* __restrict__ po, float* __restrict__ mlm, float* __restrict__ mll) {
  __shared__ __align__(16) ush Ks[64 * 128];   // [key][d], rows 256B, swz ^((row&7)<<4)
  __shared__ __align__(16) ush VTs[128 * 64];  // [d][key], rows 128B, swz ^((d&7)<<4)
  __shared__ __align__(16) ush Ps[4 * 16 * 64]; // per-wave 16x64, rows 128B, swz

  const int tid = threadIdx.x, lane = tid & 63, wave = tid >> 6;
  const int lr = lane & 15, lg = lane >> 4;
  const int qb = blockIdx.x;
  const int yy = blockIdx.y, bh = yy >> 2, half = yy & 3;
  const int b = bh / NH, h = bh % NH;
  const int k0 = half * 256;
  const float cexp = 1.4426950408889634f / sqrtf((float)NHD);

  // Q fragments (A-side: row = lr)
  int tq = b * NS + qb * 64 + wave * 16 + lr;
  short8 qf[4];
#pragma unroll
  for (int kk = 0; kk < 4; ++kk)
    qf[kk] = *(const short8*)(Qg + (size_t)tq * NW + h * NHD + kk * 32 + lg * 8);

  f32x4 accv[8] = {};
  float mr[4] = {-3.0e38f, -3.0e38f, -3.0e38f, -3.0e38f};
  float ls[4] = {};

  for (int kt = 0; kt < 4; ++kt) {   // 4 x 64 keys
    __syncthreads();
#pragma unroll
    for (int p = 0; p < 4; ++p) {    // K tile 64x128 (16KB)
      int o = p * 4096 + tid * 16;
      int row = o >> 8, cb = o & 255;
      gload16((const char*)Kg + ((size_t)(b * NS + k0 + kt * 64 + row) * NW + h * NHD) * 2 +
                  (cb ^ ((row & 7) << 4)),
              (char*)Ks + o);
    }
#pragma unroll
    for (int p = 0; p < 4; ++p) {    // V^T tile 128x64 (16KB)
      int o = p * 4096 + tid * 16;
      int d = o >> 7, cb = o & 127;
      gload16((const char*)VTg + ((size_t)(bh * NHD + d) * NS + k0 + kt * 64) * 2 +
                  (cb ^ ((d & 7) << 4)),
              (char*)VTs + o);
    }
    __syncthreads();

    // scores S[q=lg*4+r][key=kg*16+lr]
    f32x4 s[4] = {};
#pragma unroll
    for (int kg = 0; kg < 4; ++kg)
#pragma unroll
      for (int kk = 0; kk < 4; ++kk) {
        int row = kg * 16 + lr;
        short8 kf = *(const short8*)((const char*)Ks + row * 256 +
                                     ((kk * 64 + lg * 16) ^ ((row & 7) << 4)));
        s[kg] = __builtin_amdgcn_mfma_f32_16x16x32_bf16(qf[kk], kf, s[kg], 0, 0, 0);
      }

    // tile max per row
    float mt[4];
#pragma unroll
    for (int r = 0; r < 4; ++r) {
      float m0 = fmaxf(fmaxf(s[0][r], s[1][r]), fmaxf(s[2][r], s[3][r]));
#pragma unroll
      for (int mm = 1; mm < 16; mm <<= 1) m0 = fmaxf(m0, __shfl_xor(m0, mm));
      mt[r] = m0;
    }
    // defer-max: rescale only when some row's max grew past threshold
    bool need = (mt[0] > mr[0] + 8.f) || (mt[1] > mr[1] + 8.f) ||
                (mt[2] > mr[2] + 8.f) || (mt[3] > mr[3] + 8.f);
    if (__any(need)) {
#pragma unroll
      for (int r = 0; r < 4; ++r) {
        float mn = fmaxf(mr[r], mt[r]);
        float sc = exp2f((mr[r] - mn) * cexp);
        mr[r] = mn; ls[r] *= sc;
#pragma unroll
        for (int dg = 0; dg < 8; ++dg) accv[dg][r] *= sc;
      }
    }

    // P -> LDS (per-wave private, swizzled); ls accumulates lane-partial sums
    char* pw = (char*)Ps + wave * 2048;
#pragma unroll
    for (int kg = 0; kg < 4; ++kg)
#pragma unroll
      for (int r = 0; r < 4; ++r) {
        float p = exp2f((s[kg][r] - mr[r]) * cexp);
        ls[r] += p;
        int row = lg * 4 + r;
        *(ush*)(pw + row * 128 + (((kg * 16 + lr) * 2) ^ ((row & 7) << 4))) = f2b(p);
      }
    short8 pf[2];
#pragma unroll
    for (int kk2 = 0; kk2 < 2; ++kk2)
      pf[kk2] = *(const short8*)(pw + lr * 128 + ((kk2 * 64 + lg * 16) ^ ((lr & 7) << 4)));

    // PV: O[q][d] += P(16x64) * V(64x128)
#pragma unroll
    for (int dg = 0; dg < 8; ++dg) {
      int d = dg * 16 + lr;
#pragma unroll
      for (int kk2 = 0; kk2 < 2; ++kk2) {
        short8 vf = *(const short8*)((const char*)VTs + d * 128 +
                                     ((kk2 * 64 + lg * 16) ^ ((d & 7) << 4)));
        accv[dg] = __builtin_amdgcn_mfma_f32_16x16x32_bf16(pf[kk2], vf, accv[dg], 0, 0, 0);
      }
    }
  }

  // reduce lane-partial l across the 16-lane row group (once)
#pragma unroll
  for (int r = 0; r < 4; ++r)
#pragma unroll
    for (int mm = 1; mm < 16; mm <<= 1) ls[r] += __shfl_xor(ls[r], mm);

  // write unnormalized partial O + (m,l)
  size_t base = (size_t)(bh * 4 + half) * NS;
#pragma unroll
  for (int r = 0; r < 4; ++r) {
    int q = qb * 64 + wave * 16 + lg * 4 + r;
#pragma unroll
    for (int dg = 0; dg < 8; ++dg)
      po[(base + q) * NHD + dg * 16 + lr] = f2b(accv[dg][r]);
  }
  if (lr == 0) {
#pragma unroll
    for (int r = 0; r < 4; ++r) {
      int q = qb * 64 + wave * 16 + lg * 4 + r;
      mlm[base + q] = mr[r];
      mll[base + q] = ls[r];
    }
  }
}

// ---------------- combine 4 KV-split partials -> AO (bf16) ----------------
__global__ __launch_bounds__(256, 4)
void attn_combine(const ush* __restrict__ po, const float* __restrict__ mlm,
                  const float* __restrict__ mll, ush* __restrict__ ao) {
  const float cexp = 1.4426950408889634f / sqrtf((float)NHD);
  int idx = blockIdx.x * 256 + threadIdx.x;   // NBH*NS*16 threads
  int row = idx >> 4, dq = idx & 15;
  int bh = row >> 10, q = row & 1023;
  int b = bh / NH, hh = bh % NH;
  float m[4], l[4], M = -3.0e38f;
#pragma unroll
  for (int h = 0; h < 4; ++h) {
    m[h] = mlm[(size_t)(bh * 4 + h) * NS + q];
    l[h] = mll[(size_t)(bh * 4 + h) * NS + q];
    M = fmaxf(M, m[h]);
  }
  float L = 0.0f, w[4];
#pragma unroll
  for (int h = 0; h < 4; ++h) { w[h] = exp2f((m[h] - M) * cexp); L += l[h] * w[h]; }
  float inv = 1.0f / L;
  float o[8] = {};
#pragma unroll
  for (int h = 0; h < 4; ++h) {
    short8 v = *(const short8*)(po + ((size_t)(bh * 4 + h) * NS + q) * NHD + dq * 8);
#pragma unroll
    for (int j = 0; j < 8; ++j) o[j] += b2f((ush)v[j]) * w[h];
  }
  short8 res;
#pragma unroll
  for (int j = 0; j < 8; ++j) res[j] = (short)f2b(o[j] * inv);
  *(short8*)(ao + ((size_t)(b * NS + q)) * NW + hh * NHD + dq * 8) = res;
}

// ---------------- residual + RMSNorm: x1 = rmsnorm(x + oo0 + oo1) -> bf16 ----------------
__global__ __launch_bounds__(256, 4)
void rmsnorm_res(const float* __restrict__ x, const ush* __restrict__ oo,
                 ush* __restrict__ x1b) {
  const size_t TOT = (size_t)NTOK * NW;
  __shared__ float red[4];
  int t = blockIdx.x, c = threadIdx.x;
  int lane = c & 63, wave = c >> 6;
  float v[3]; float ss = 0.0f;
#pragma unroll
  for (int i = 0; i < 3; ++i) {
    int col = c + i * 256;
    float a = x[(size_t)t * ND + col] + b2f(oo[(size_t)t * NW + col]) +
              b2f(oo[TOT + (size_t)t * NW + col]);
    v[i] = a; ss += a * a;
  }
#pragma unroll
  for (int m = 1; m < 64; m <<= 1) ss += __shfl_xor(ss, m);
  if (lane == 0) red[wave] = ss;
  __syncthreads();
  float tot = red[0] + red[1] + red[2] + red[3];
  float scale = rsqrtf(tot / (float)NW + EPS);
#pragma unroll
  for (int i = 0; i < 3; ++i) {
    int col = c + i * 256;
    x1b[(size_t)t * NW + col] = f2b(v[i] * scale);
  }
}

// ---------------- final: rmsnorm(x1 + sum(ffp)) * gate -> accumulate out ----------------
__global__ __launch_bounds__(256, 4)
void final_acc(const ush* __restrict__ x1b, const ush* __restrict__ ffp,
               const float* __restrict__ gate, int e, float* __restrict__ out) {
  const size_t TOT = (size_t)NTOK * NW;
  int t = blockIdx.x;
  float g = gate[(size_t)t * NE + e];
  if (g == 0.0f) return;
  __shared__ float red[4];
  int c = threadIdx.x, lane = c & 63, wave = c >> 6;
  float v[3]; float ss = 0.0f;
#pragma unroll
  for (int i = 0; i < 3; ++i) {
    int col = c + i * 256;
    float f = b2f(ffp[(size_t)t * NW + col]) + b2f(ffp[TOT + (size_t)t * NW + col]) +
              b2f(ffp[2 * TOT + (size_t)t * NW + col]) + b2f(ffp[3 * TOT + (size_t)t * NW + col]);
    float a = b2f(x1b[(size_t)t * NW + col]) + f;
    v[i] = a; ss += a * a;
  }
#pragma unroll
  for (int m = 1; m < 64; m <<= 1) ss += __shfl_xor(ss, m);
  if (lane == 0) red[wave] = ss;
  __syncthreads();
  float tot = red[0] + red[1] + red[2] + red[3];
  float scale = rsqrtf(tot / (float)NW + EPS) * g;
#pragma unroll
  for (int i = 0; i < 3; ++i) {
    int col = c + i * 256;
    out[(size_t)t * ND + col] += v[i] * scale;
  }
}

// ---------------- host ----------------
extern "C" void kernel_launch(void* const* d_in, const int* in_sizes, int n_in,
                              void* d_out, int out_size, void* d_ws, size_t ws_size,
                              hipStream_t stream) {
  (void)in_sizes; (void)n_in; (void)ws_size;
  const float* x  = (const float*)d_in[0];
  const float* wr = (const float*)d_in[1];
  const float* qw = (const float*)d_in[2];
  const float* qbias = (const float*)d_in[3];
  const float* kw = (const float*)d_in[4];
  const float* kbias = (const float*)d_in[5];
  const float* vw = (const float*)d_in[6];
  const float* vbias = (const float*)d_in[7];
  const float* ow = (const float*)d_in[8];
  const float* obias = (const float*)d_in[9];
  const float* w1 = (const float*)d_in[10];
  const float* b1 = (const float*)d_in[11];
  const float* w2 = (const float*)d_in[12];
  const float* b2 = (const float*)d_in[13];
  float* out = (float*)d_out;
  char* ws = (char*)d_ws;

  size_t off = 0;
  auto alloc = [&](size_t bytes) {
    void* p = ws + off;
    off += (bytes + 255) & ~(size_t)255;
    return p;
  };
  float* gate = (float*)alloc((size_t)NTOK * NE * 4);
  ush* xs  = (ush*)alloc((size_t)NTOK * NW * 2);
  ush* wqb = (ush*)alloc((size_t)NW * NW * 2);
  ush* wkb = (ush*)alloc((size_t)NW * NW * 2);
  ush* wvb = (ush*)alloc((size_t)NW * NW * 2);
  ush* wob = (ush*)alloc((size_t)NW * NW * 2);
  ush* w1b = (ush*)alloc((size_t)NF * NW * 2);
  ush* w2b = (ush*)alloc((size_t)NW * NF * 2);
  ush* x1b = (ush*)alloc((size_t)NTOK * NW * 2);
  // phase-aliased scratch block (58.8 MB):
  //  attn phase: [ao 0-6.3M][kg 6.3-12.6][vt 12.6-18.9][po 18.9-44.0][mlm/mll 44.0-44.8][oo 44.8-57.4]
  //              qg shares slot 0 with ao (qg dead after attn2; ao written by combine after)
  //  ffn  phase: [hb 0-33.6][ffp 33.6-58.8]  (all attn-phase buffers dead)
  char* scr = (char*)alloc(58720256 + 1048576);
  ush* qg   = (ush*)scr;
  ush* kg   = (ush*)(scr + 6291456);
  ush* vtg  = (ush*)(scr + 12582912);
  ush* po   = (ush*)(scr + 18874368);
  float* mlm = (float*)(scr + 44040192);
  float* mll = (float*)(scr + 44433408);
  ush* ooP  = (ush*)(scr + 44826624);      // 2 partials x 4096*768 bf16 -> ends 57409536
  ush* aog  = (ush*)scr;                   // combine output over dead qg
  ush* hb   = (ush*)scr;                   // ffn phase
  ush* ffp  = (ush*)(scr + 33554432);      // 4 partials -> ends 58720256

  hipMemsetAsync(d_out, 0, (size_t)out_size * 4, stream);
  router_kernel<<<dim3(NTOK / 4), 256, 0, stream>>>(x, wr, gate);
  cast2d<<<dim3(1024), 256, 0, stream>>>(x, ND, NTOK, NW / 4, xs);

  for (int e = 0; e < NE; ++e) {
    cast_expert<<<dim3(2048), 256, 0, stream>>>(
        qw + (size_t)e * ND * ND, kw + (size_t)e * ND * ND,
        vw + (size_t)e * ND * ND, ow + (size_t)e * ND * ND,
        w1 + (size_t)e * NF * ND, w2 + (size_t)e * ND * NF,
        wqb, wkb, wvb, wob, w1b, w2b);

    // QKV fused (z=0:Q, z=1:K, z=2:V -> V^T layout)
    gemm_bt<3><<<dim3(32, 6, 3), 256, 0, stream>>>(
        xs, wqb, wkb, wvb,
        qbias + (size_t)e * ND, kbias + (size_t)e * ND, vbias + (size_t)e * ND,
        qg, kg, vtg, NTOK, NW, NW, NW, 0);

    attn2<<<dim3(16, NBH * 4), 256, 0, stream>>>(qg, kg, vtg, po, mlm, mll);
    attn_combine<<<dim3(NBH * NS * 16 / 256), 256, 0, stream>>>(po, mlm, mll, aog);

    // O-proj, split-K x2 -> bf16 partials
    gemm_bt<0><<<dim3(32, 6, 2), 256, 0, stream>>>(
        aog, wob, wob, wob,
        obias + (size_t)e * ND, nullptr, nullptr,
        ooP, ooP, ooP, NTOK, NW, NW, 384, 1);

    rmsnorm_res<<<dim3(NTOK), 256, 0, stream>>>(x, ooP, x1b);

    // FFN1 (full K)
    gemm_bt<2><<<dim3(32, 32, 1), 256, 0, stream>>>(
        x1b, w1b, w1b, w1b,
        b1 + (size_t)e * NF, nullptr, nullptr,
        hb, hb, hb, NTOK, NF, NW, NW, 0);

    // FFN2, split-K x4 -> bf16 partials
    gemm_bt<0><<<dim3(32, 6, 4), 256, 0, stream>>>(
        hb, w2b, w2b, w2b,
        b2 + (size_t)e * ND, nullptr, nullptr,
        ffp, ffp, ffp, NTOK, NW, NF, 1024, 1);

    final_acc<<<dim3(NTOK), 256, 0, stream>>>(x1b, ffp, gate, e, out);
  }
}